// Round 5
// baseline (114.531 us; speedup 1.0000x reference)
//
#include <hip/hip_runtime.h>
#include <hip/hip_bf16.h>

// Deformable conv2d (v1, align_corners=True, zeros padding), fused
// NHWC-bf16 gather + MFMA. R5: 2D 8x8-patch blocks (wave = 4x4 pixels) so the
// per-block gather working set (~21 KB) fits L1 and each x line is reused ~9x
// from L1 instead of re-fetched from L2 (R2-R4 invariant wall: 302 MB of
// random 64B lines through L2 at every structure ≈ 45 µs).
// All 9 kn of A-fragments staged to LDS once (72 KB, one barrier total);
// kn loop is barrier-free.
// x(4,64,128,128) f32, offset(4,18,128,128) f32, weight(64,64,9) f32
// -> out(4,64,128,128) f32.  iy = oh + off_y, ix = ow + off_x.

#define NB 4
#define CI 64
#define HH 128
#define WW 128
#define OCH 64
#define KNN 9
#define HW (HH * WW)

typedef unsigned int u32;
typedef unsigned short u16;
typedef __attribute__((ext_vector_type(8))) short bf16x8;
typedef __attribute__((ext_vector_type(4))) float f32x4;

typedef const __attribute__((address_space(1))) u32* gas_ptr;
typedef __attribute__((address_space(3))) u32* las_ptr;

__device__ inline u16 f2bf(float f) {  // RNE
    u32 u = __float_as_uint(f);
    return (u16)((u + 0x7fffu + ((u >> 16) & 1u)) >> 16);
}
__device__ inline u32 pk2(float lo, float hi) {
    return (u32)f2bf(lo) | ((u32)f2bf(hi) << 16);
}
__device__ inline void up2(u32 u, float& lo, float& hi) {
    lo = __uint_as_float(u << 16);
    hi = __uint_as_float(u & 0xffff0000u);
}
__device__ inline void gload_lds16(const u16* g, u16* s) {
    __builtin_amdgcn_global_load_lds((gas_ptr)g, (las_ptr)s, 16, 0, 0);
}

// ---- prologue: x NCHW f32 -> NHWC bf16, + weight -> A-fragment order bf16.
// wf layout: frag[kn][chunk(2)][strip(4)][lane(64)][j(8)]; lane holds
// A[m=lane&15][k=(lane>>4)*8+j], oc = strip*16+m, c = chunk*32+k.
__global__ __launch_bounds__(256) void prep_kernel(const float* __restrict__ x,
                                                   const float* __restrict__ w,
                                                   u16* __restrict__ xT,
                                                   u16* __restrict__ wf) {
    __shared__ float T[64 * 68];
    const int tid = threadIdx.x;
    if (blockIdx.x < NB * 256) {
        const int n = blockIdx.x >> 8;
        const int hw0 = (blockIdx.x & 255) << 6;
#pragma unroll
        for (int jj = 0; jj < 4; jj++) {
            int c = (tid >> 4) + (jj << 4);
            int hwq = (tid & 15) << 2;
            float4 v = *(const float4*)&x[(((n << 6) + c) << 14) + hw0 + hwq];
            *(float4*)&T[c * 68 + hwq] = v;
        }
        __syncthreads();
        const int hw_l = tid >> 2;
        const int cb = (tid & 3) << 4;
        u32 ou[8];
#pragma unroll
        for (int k = 0; k < 8; k++) {
            ou[k] = pk2(T[(cb + 2 * k) * 68 + hw_l], T[(cb + 2 * k + 1) * 68 + hw_l]);
        }
        u16* dst = xT + ((size_t)((n << 14) + hw0 + hw_l) << 6) + cb;
        *(uint4*)dst = make_uint4(ou[0], ou[1], ou[2], ou[3]);
        *(uint4*)(dst + 8) = make_uint4(ou[4], ou[5], ou[6], ou[7]);
    } else {
        int i = (blockIdx.x - NB * 256) * 256 + tid;
        if (i < KNN * 2 * 4 * 64 * 8) {
            int j = i & 7, l = (i >> 3) & 63, strip = (i >> 9) & 3,
                chunk = (i >> 11) & 1, kn = i >> 12;
            int oc = strip * 16 + (l & 15);
            int c = chunk * 32 + ((l >> 4) & 3) * 8 + j;
            wf[i] = f2bf(w[(oc * CI + c) * KNN + kn]);
        }
    }
}

// ---- main kernel: block = 8x8 pixel patch (4 waves of 4x4), 64 oc.
__global__ __launch_bounds__(256, 2) void dcn_main_kernel(const u16* __restrict__ xT,
                                                          const float* __restrict__ off,
                                                          const u16* __restrict__ wf,
                                                          float* __restrict__ out) {
    __shared__ __align__(16) u16 Abuf[KNN * 4096];  // all 9 kn A-fragments, 72 KB
    const int tid = threadIdx.x;
    const int l = tid & 63;
    const int wv = tid >> 6;

    // stage all A-fragments to LDS once (coalesced, 18 x 16B per thread)
    {
        const u16* g = wf + tid * 8;
        u16* s = Abuf + tid * 8;
#pragma unroll
        for (int i = 0; i < 18; i++) {
            gload_lds16(g + i * 2048, s + i * 2048);  // 2048 u16 = 256 threads * 8
        }
    }

    // pixel decode: 2D patch
    const int n = blockIdx.x >> 8;
    const int patch = blockIdx.x & 255;               // 16x16 patches of 8x8
    const int py = ((patch >> 4) << 3), px = ((patch & 15) << 3);
    const int qy = ((wv >> 1) << 2), qx = ((wv & 1) << 2);
    const int col = l & 15;
    const int oh = py + qy + (col >> 2);
    const int ow = px + qx + (col & 3);
    const int rr = (oh << 7) + ow;
    const int cbase = (l >> 4) << 3;  // 0,8,16,24
    const u16* xTn = xT + ((size_t)n << 20);
    const float* offn = off + n * (2 * KNN * HW);

    // preload all 18 offsets
    float offy[KNN], offx[KNN];
#pragma unroll
    for (int kn = 0; kn < KNN; kn++) {
        offy[kn] = offn[(2 * kn) * HW + rr];
        offx[kn] = offn[(2 * kn + 1) * HW + rr];
    }

    __syncthreads();  // A-fragments resident

    f32x4 acc[4] = {{0, 0, 0, 0}, {0, 0, 0, 0}, {0, 0, 0, 0}, {0, 0, 0, 0}};

#pragma unroll
    for (int kn = 0; kn < KNN; kn++) {
        float iy = (float)oh + offy[kn], ix = (float)ow + offx[kn];
        float y0f = floorf(iy), x0f = floorf(ix);
        float wy1 = iy - y0f, wy0 = 1.f - wy1;
        float wx1 = ix - x0f, wx0 = 1.f - wx1;
        float my0 = (y0f >= 0.f && y0f <= 127.f) ? 1.f : 0.f;
        float my1 = (y0f >= -1.f && y0f <= 126.f) ? 1.f : 0.f;
        float mx0 = (x0f >= 0.f && x0f <= 127.f) ? 1.f : 0.f;
        float mx1 = (x0f >= -1.f && x0f <= 126.f) ? 1.f : 0.f;
        float W0 = wy0 * wx0 * my0 * mx0, W1 = wy0 * wx1 * my0 * mx1;
        float W2 = wy1 * wx0 * my1 * mx0, W3 = wy1 * wx1 * my1 * mx1;
        int y0 = min(max((int)y0f, 0), 127), y1 = min(max((int)y0f + 1, 0), 127);
        int x0 = min(max((int)x0f, 0), 127), x1 = min(max((int)x0f + 1, 0), 127);
        int O0 = ((y0 << 7) + x0) << 6, O1 = ((y0 << 7) + x1) << 6;
        int O2 = ((y1 << 7) + x0) << 6, O3 = ((y1 << 7) + x1) << 6;

#pragma unroll
        for (int ch = 0; ch < 2; ch++) {
            const int c = (ch << 5) + cbase;
            uint4 q0 = *(const uint4*)(xTn + O0 + c);
            uint4 q1 = *(const uint4*)(xTn + O1 + c);
            uint4 q2 = *(const uint4*)(xTn + O2 + c);
            uint4 q3 = *(const uint4*)(xTn + O3 + c);
            const u32* a0 = (const u32*)&q0;
            const u32* a1 = (const u32*)&q1;
            const u32* a2 = (const u32*)&q2;
            const u32* a3 = (const u32*)&q3;
            union { u32 u[4]; bf16x8 v; } B;
#pragma unroll
            for (int k = 0; k < 4; k++) {
                float p0l, p0h, p1l, p1h, p2l, p2h, p3l, p3h;
                up2(a0[k], p0l, p0h);
                up2(a1[k], p1l, p1h);
                up2(a2[k], p2l, p2h);
                up2(a3[k], p3l, p3h);
                float slo = p0l * W0 + p1l * W1 + p2l * W2 + p3l * W3;
                float shi = p0h * W0 + p1h * W1 + p2h * W2 + p3h * W3;
                B.u[k] = pk2(slo, shi);
            }
#pragma unroll
            for (int s = 0; s < 4; s++) {
                bf16x8 A = *(const bf16x8*)&Abuf[(((kn << 1) + ch) << 2 | s) * 512 + l * 8];
                acc[s] = __builtin_amdgcn_mfma_f32_16x16x32_bf16(A, B.v, acc[s], 0, 0, 0);
            }
        }
    }

    // epilogue: D layout col(pixel)=l&15, row(oc-in-strip)=(l>>4)*4+reg
    const int rq = l >> 4;
    float* op = out + ((size_t)(n * OCH) << 14);
#pragma unroll
    for (int s = 0; s < 4; s++) {
        const int ocb = (s << 4) + (rq << 2);
#pragma unroll
        for (int g = 0; g < 4; g++) {
            op[((ocb + g) << 14) + rr] = acc[s][g];
        }
    }
}

// ---- fallback (ws too small): round-1 style direct kernel
__global__ __launch_bounds__(256) void dcn_fallback_kernel(
    const float* __restrict__ x, const float* __restrict__ off,
    const float* __restrict__ w, float* __restrict__ out) {
    int p = blockIdx.x * blockDim.x + threadIdx.x;
    int n = p / HW, r = p % HW, oh = r / WW, ow = r % WW;
    float acc[OCH];
#pragma unroll
    for (int i = 0; i < OCH; i++) acc[i] = 0.f;
    const float* xn = x + n * (CI * HW);
    const float* offn = off + n * (2 * KNN * HW);
    for (int kn = 0; kn < KNN; kn++) {
        float iy = (float)oh + offn[(2 * kn) * HW + r];
        float ix = (float)ow + offn[(2 * kn + 1) * HW + r];
        float y0f = floorf(iy), x0f = floorf(ix);
        float wy1 = iy - y0f, wy0 = 1.f - wy1, wx1 = ix - x0f, wx0 = 1.f - wx1;
        float my0 = (y0f >= 0.f && y0f <= 127.f) ? 1.f : 0.f;
        float my1 = (y0f >= -1.f && y0f <= 126.f) ? 1.f : 0.f;
        float mx0 = (x0f >= 0.f && x0f <= 127.f) ? 1.f : 0.f;
        float mx1 = (x0f >= -1.f && x0f <= 126.f) ? 1.f : 0.f;
        float w00 = wy0 * wx0 * my0 * mx0, w01 = wy0 * wx1 * my0 * mx1;
        float w10 = wy1 * wx0 * my1 * mx0, w11 = wy1 * wx1 * my1 * mx1;
        int y0 = min(max((int)y0f, 0), 127), y1 = min(max((int)y0f + 1, 0), 127);
        int x0 = min(max((int)x0f, 0), 127), x1 = min(max((int)x0f + 1, 0), 127);
        int o00 = y0 * WW + x0, o01 = y0 * WW + x1, o10 = y1 * WW + x0, o11 = y1 * WW + x1;
        for (int c = 0; c < CI; c++) {
            const float* xc = xn + c * HW;
            float s = xc[o00] * w00 + xc[o01] * w01 + xc[o10] * w10 + xc[o11] * w11;
#pragma unroll
            for (int oc = 0; oc < OCH; oc++) acc[oc] += w[(oc * CI + c) * KNN + kn] * s;
        }
    }
    float* outp = out + n * (OCH * HW) + r;
#pragma unroll
    for (int oc = 0; oc < OCH; oc++) outp[oc * HW] = acc[oc];
}

extern "C" void kernel_launch(void* const* d_in, const int* in_sizes, int n_in,
                              void* d_out, int out_size, void* d_ws, size_t ws_size,
                              hipStream_t stream) {
    const float* x = (const float*)d_in[0];
    const float* off = (const float*)d_in[1];
    const float* w = (const float*)d_in[2];
    float* out = (float*)d_out;

    const size_t xT_elems = (size_t)NB * HW * CI;             // 4,194,304 u16
    const size_t wf_elems = (size_t)KNN * 2 * 4 * 64 * 8;     // 36,864 u16
    const size_t need = (xT_elems + wf_elems) * sizeof(u16);  // ~8.46 MB

    if (ws_size >= need) {
        u16* xT = (u16*)d_ws;
        u16* wfr = xT + xT_elems;
        const int wf_blocks = (int)((wf_elems + 255) / 256);  // 144
        prep_kernel<<<NB * 256 + wf_blocks, 256, 0, stream>>>(x, w, xT, wfr);
        dcn_main_kernel<<<NB * 256, 256, 0, stream>>>(xT, off, wfr, out);
    } else {
        dcn_fallback_kernel<<<(NB * HW) / 256, 256, 0, stream>>>(x, off, w, out);
    }
}